// Round 1
// baseline (837.712 us; speedup 1.0000x reference)
//
#include <hip/hip_runtime.h>
#include <hip/hip_bf16.h>
#include <math.h>

// Problem constants (match reference)
#define NN   50000
#define EE   800000
#define INF_ 512
#define ENC  256
#define HID  32
#define HEADS 4
#define OUTC 40
#define SLOPE 0.2f

// ---------------------------------------------------------------------------
// Generic tiled f32 GEMM: C[M,N] = A[M,K] @ B[K,N] (+bias) (+relu)
// BM=BN=64, BK=16, 256 threads, 4x4 per thread. K must be a multiple of 16.
// ---------------------------------------------------------------------------
template<bool RELU>
__global__ __launch_bounds__(256) void gemm_bias(const float* __restrict__ A,
                                                 const float* __restrict__ B,
                                                 const float* __restrict__ bias,
                                                 float* __restrict__ C,
                                                 int M, int N, int K) {
    __shared__ float As[16][65];   // [k][m], +1 pad
    __shared__ float Bs[16][64];   // [k][n], unpadded (float4-aligned, 2-way is free)
    int tid = threadIdx.x;
    int tx = tid & 15, ty = tid >> 4;
    int bm = blockIdx.y * 64, bn = blockIdx.x * 64;
    int arow = tid >> 2, acol = (tid & 3) << 2;   // A tile: 64 rows x 16 cols
    int brow = tid >> 4, bcol = (tid & 15) << 2;  // B tile: 16 rows x 64 cols
    bool fullM = (bm + 64 <= M);
    bool fullN = (bn + 64 <= N);
    float acc[4][4] = {{0.f}};

    for (int k0 = 0; k0 < K; k0 += 16) {
        if (fullM) {
            const float4 av = *(const float4*)(A + (size_t)(bm + arow) * K + (k0 + acol));
            As[acol + 0][arow] = av.x; As[acol + 1][arow] = av.y;
            As[acol + 2][arow] = av.z; As[acol + 3][arow] = av.w;
        } else {
            int r = bm + arow;
            #pragma unroll
            for (int i = 0; i < 4; i++)
                As[acol + i][arow] = (r < M) ? A[(size_t)r * K + k0 + acol + i] : 0.f;
        }
        if (fullN) {
            *(float4*)(&Bs[brow][bcol]) = *(const float4*)(B + (size_t)(k0 + brow) * N + (bn + bcol));
        } else {
            #pragma unroll
            for (int i = 0; i < 4; i++) {
                int c = bn + bcol + i;
                Bs[brow][bcol + i] = (c < N) ? B[(size_t)(k0 + brow) * N + c] : 0.f;
            }
        }
        __syncthreads();
        #pragma unroll
        for (int kk = 0; kk < 16; kk++) {
            float a[4], b[4];
            #pragma unroll
            for (int i = 0; i < 4; i++) a[i] = As[kk][ty * 4 + i];
            #pragma unroll
            for (int j = 0; j < 4; j++) b[j] = Bs[kk][tx * 4 + j];
            #pragma unroll
            for (int i = 0; i < 4; i++)
                #pragma unroll
                for (int j = 0; j < 4; j++) acc[i][j] += a[i] * b[j];
        }
        __syncthreads();
    }

    #pragma unroll
    for (int i = 0; i < 4; i++) {
        int r = bm + ty * 4 + i;
        if (r < M) {
            #pragma unroll
            for (int j = 0; j < 4; j++) {
                int c = bn + tx * 4 + j;
                if (c < N) {
                    float v = acc[i][j] + (bias ? bias[c] : 0.f);
                    if (RELU) v = fmaxf(v, 0.f);
                    C[(size_t)r * N + c] = v;
                }
            }
        }
    }
}

// ---------------------------------------------------------------------------
// CSR build (by destination, with implicit self-loop in the last slot)
// ---------------------------------------------------------------------------
__global__ void count_deg(const int* __restrict__ dstA, int E, int* __restrict__ deg) {
    int e = blockIdx.x * blockDim.x + threadIdx.x;
    if (e < E) atomicAdd(&deg[dstA[e]], 1);
}

// Single-block inclusive scan: offs[n+1] = offs[n] + deg[n] + 1 (self loop).
// Also writes cur[n] = offs[n] (scatter cursor).
__global__ void scan_kernel(const int* __restrict__ deg, int* __restrict__ offs,
                            int* __restrict__ cur, int N) {
    __shared__ int buf[1024];
    __shared__ int base_s;
    int t = threadIdx.x;
    if (t == 0) { offs[0] = 0; base_s = 0; }
    __syncthreads();
    for (int start = 0; start < N; start += 1024) {
        int i = start + t;
        int v = (i < N) ? deg[i] + 1 : 0;
        buf[t] = v;
        __syncthreads();
        for (int o = 1; o < 1024; o <<= 1) {
            int add = (t >= o) ? buf[t - o] : 0;
            __syncthreads();
            buf[t] += add;
            __syncthreads();
        }
        int incl = buf[t];
        int total = buf[1023];
        int base = base_s;
        __syncthreads();
        if (i < N) { offs[i + 1] = base + incl; cur[i] = base + incl - v; }
        __syncthreads();
        if (t == 0) base_s = base + total;
        __syncthreads();
    }
}

__global__ void scatter_k(const int* __restrict__ srcA, const int* __restrict__ dstA,
                          int E, int* __restrict__ cur, int* __restrict__ csr) {
    int e = blockIdx.x * blockDim.x + threadIdx.x;
    if (e < E) {
        int p = atomicAdd(&cur[dstA[e]], 1);
        csr[p] = srcA[e];
    }
}

__global__ void selfloop_k(const int* __restrict__ offs, int* __restrict__ csr, int N) {
    int n = blockIdx.x * blockDim.x + threadIdx.x;
    if (n < N) csr[offs[n + 1] - 1] = n;
}

// ---------------------------------------------------------------------------
// Attention score vectors
// ---------------------------------------------------------------------------
__global__ void att1(const float* __restrict__ h1, const float* __restrict__ atts,
                     const float* __restrict__ attd, float* __restrict__ as1,
                     float* __restrict__ ad1, int N) {
    int idx = blockIdx.x * blockDim.x + threadIdx.x;
    if (idx >= N * HEADS) return;
    int n = idx >> 2, h = idx & 3;
    const float* row = h1 + (size_t)n * (HEADS * HID) + h * HID;
    float ss = 0.f, dd = 0.f;
    #pragma unroll
    for (int c = 0; c < HID; c++) {
        float v = row[c];
        ss += v * atts[h * HID + c];
        dd += v * attd[h * HID + c];
    }
    as1[idx] = ss; ad1[idx] = dd;
}

__global__ void att2(const float* __restrict__ h2, const float* __restrict__ atts,
                     const float* __restrict__ attd, float* __restrict__ as2,
                     float* __restrict__ ad2, int N) {
    int n = blockIdx.x * blockDim.x + threadIdx.x;
    if (n >= N) return;
    const float* row = h2 + (size_t)n * OUTC;
    float ss = 0.f, dd = 0.f;
    #pragma unroll
    for (int c = 0; c < OUTC; c++) {
        float v = row[c];
        ss += v * atts[c];
        dd += v * attd[c];
    }
    as2[n] = ss; ad2[n] = dd;
}

// ---------------------------------------------------------------------------
// GAT1 aggregation: one 128-thread block per node. thread t = channel c,
// head h = t>>5. Softmax (max/den) per head via 32-lane butterflies, then a
// per-channel weighted gather of h1[src]. Epilogue: +gat1_b +r1 (has res1_b),
// relu -> outh.
// ---------------------------------------------------------------------------
__global__ __launch_bounds__(128) void gat1_agg(const float* __restrict__ h1,
                                                const float* __restrict__ r1,
                                                const float* __restrict__ as1,
                                                const float* __restrict__ ad1,
                                                const int* __restrict__ offs,
                                                const int* __restrict__ csr,
                                                const float* __restrict__ gb,
                                                float* __restrict__ outh, int N) {
    int n = blockIdx.x;
    int t = threadIdx.x;       // 0..127
    int h = t >> 5;            // head
    int l = t & 31;
    int beg = offs[n], d = offs[n + 1] - beg;
    float adst = ad1[n * HEADS + h];

    float mx = -INFINITY;
    for (int j = l; j < d; j += 32) {
        int s = csr[beg + j];
        float v = as1[s * HEADS + h] + adst;
        v = v >= 0.f ? v : SLOPE * v;
        mx = fmaxf(mx, v);
    }
    for (int o = 16; o; o >>= 1) mx = fmaxf(mx, __shfl_xor(mx, o, 32));

    float den = 0.f;
    for (int j = l; j < d; j += 32) {
        int s = csr[beg + j];
        float v = as1[s * HEADS + h] + adst;
        v = v >= 0.f ? v : SLOPE * v;
        den += __expf(v - mx);
    }
    for (int o = 16; o; o >>= 1) den += __shfl_xor(den, o, 32);
    den = fmaxf(den, 1e-16f);

    float acc = 0.f;
    for (int j = 0; j < d; j++) {
        int s = csr[beg + j];
        float v = as1[s * HEADS + h] + adst;
        v = v >= 0.f ? v : SLOPE * v;
        float w = __expf(v - mx);
        acc += w * h1[(size_t)s * 128 + t];
    }
    float v = acc / den + gb[t] + r1[(size_t)n * 128 + t];
    outh[(size_t)n * 128 + t] = fmaxf(v, 0.f);
}

// ---------------------------------------------------------------------------
// GAT2 aggregation: one 64-thread (1 wave) block per node, single head.
// Epilogue: +gat2_b +r2 (has res2_b) -> out.
// ---------------------------------------------------------------------------
__global__ __launch_bounds__(64) void gat2_agg(const float* __restrict__ h2,
                                               const float* __restrict__ r2,
                                               const float* __restrict__ as2,
                                               const float* __restrict__ ad2,
                                               const int* __restrict__ offs,
                                               const int* __restrict__ csr,
                                               const float* __restrict__ gb,
                                               float* __restrict__ out, int N) {
    int n = blockIdx.x;
    int t = threadIdx.x;       // 0..63
    int beg = offs[n], d = offs[n + 1] - beg;
    float adst = ad2[n];

    float mx = -INFINITY;
    for (int j = t; j < d; j += 64) {
        int s = csr[beg + j];
        float v = as2[s] + adst;
        v = v >= 0.f ? v : SLOPE * v;
        mx = fmaxf(mx, v);
    }
    for (int o = 32; o; o >>= 1) mx = fmaxf(mx, __shfl_xor(mx, o, 64));

    float den = 0.f;
    for (int j = t; j < d; j += 64) {
        int s = csr[beg + j];
        float v = as2[s] + adst;
        v = v >= 0.f ? v : SLOPE * v;
        den += __expf(v - mx);
    }
    for (int o = 32; o; o >>= 1) den += __shfl_xor(den, o, 64);
    den = fmaxf(den, 1e-16f);

    if (t < OUTC) {
        float acc = 0.f;
        for (int j = 0; j < d; j++) {
            int s = csr[beg + j];
            float v = as2[s] + adst;
            v = v >= 0.f ? v : SLOPE * v;
            float w = __expf(v - mx);
            acc += w * h2[(size_t)s * OUTC + t];
        }
        out[(size_t)n * OUTC + t] = acc / den + gb[t] + r2[(size_t)n * OUTC + t];
    }
}

// ---------------------------------------------------------------------------
// Launcher
// ---------------------------------------------------------------------------
extern "C" void kernel_launch(void* const* d_in, const int* in_sizes, int n_in,
                              void* d_out, int out_size, void* d_ws, size_t ws_size,
                              hipStream_t stream) {
    const float* x      = (const float*)d_in[0];
    const int*   ei     = (const int*)d_in[1];
    const float* ae_w1  = (const float*)d_in[2];
    const float* ae_b1  = (const float*)d_in[3];
    const float* ae_w2  = (const float*)d_in[4];
    const float* ae_b2  = (const float*)d_in[5];
    const float* gat1_w = (const float*)d_in[6];
    const float* g1as   = (const float*)d_in[7];
    const float* g1ad   = (const float*)d_in[8];
    const float* g1b    = (const float*)d_in[9];
    const float* gat2_w = (const float*)d_in[10];
    const float* g2as   = (const float*)d_in[11];
    const float* g2ad   = (const float*)d_in[12];
    const float* g2b    = (const float*)d_in[13];
    const float* res1_w = (const float*)d_in[14];
    const float* res1_b = (const float*)d_in[15];
    const float* res2_w = (const float*)d_in[16];
    const float* res2_b = (const float*)d_in[17];
    float* out = (float*)d_out;

    const int N = in_sizes[0] / INF_;       // 50000
    const int E = in_sizes[1] / 2;          // 800000
    const int Etot = E + N;

    const int* srcA = ei;
    const int* dstA = ei + E;

    // Workspace layout (floats then ints)
    float* ws = (float*)d_ws;
    size_t off = 0;
    float* y1 = ws + off; off += (size_t)N * ENC;            // slot A (reused: h1|r1)
    float* xe = ws + off; off += (size_t)N * ENC;            // slot B (reused: hbuf|h2|r2)
    float* as1 = ws + off; off += (size_t)N * HEADS;
    float* ad1 = ws + off; off += (size_t)N * HEADS;
    float* as2 = ws + off; off += (size_t)N;
    float* ad2 = ws + off; off += (size_t)N;
    int* ibase = (int*)(ws + off);
    int* deg  = ibase;                  // N
    int* offs = deg + N;                // N+1
    int* cur  = offs + (N + 1);         // N
    int* csr  = cur + N;                // Etot

    // Aliases (after producer done, source freed)
    float* h1   = y1;                         // [N,128]
    float* r1   = y1 + (size_t)N * 128;       // [N,128]
    float* hbuf = xe;                         // [N,128]
    float* h2   = xe + (size_t)N * 128;       // [N,40]
    float* r2   = h2 + (size_t)N * OUTC;      // [N,40]

    // --- CSR build ---
    hipMemsetAsync(deg, 0, (size_t)N * sizeof(int), stream);
    count_deg<<<(E + 255) / 256, 256, 0, stream>>>(dstA, E, deg);
    scan_kernel<<<1, 1024, 0, stream>>>(deg, offs, cur, N);
    scatter_k<<<(E + 255) / 256, 256, 0, stream>>>(srcA, dstA, E, cur, csr);
    selfloop_k<<<(N + 255) / 256, 256, 0, stream>>>(offs, csr, N);

    // --- Autoencoder ---
    {
        dim3 g((ENC + 63) / 64, (N + 63) / 64);
        gemm_bias<true><<<g, 256, 0, stream>>>(x, ae_w1, ae_b1, y1, N, ENC, INF_);
        gemm_bias<true><<<g, 256, 0, stream>>>(y1, ae_w2, ae_b2, xe, N, ENC, ENC);
    }
    // --- GAT1 linear + residual linear ---
    {
        dim3 g((128 + 63) / 64, (N + 63) / 64);
        gemm_bias<false><<<g, 256, 0, stream>>>(xe, gat1_w, nullptr, h1, N, 128, ENC);
        gemm_bias<false><<<g, 256, 0, stream>>>(xe, res1_w, res1_b, r1, N, 128, ENC);
    }
    att1<<<(N * HEADS + 255) / 256, 256, 0, stream>>>(h1, g1as, g1ad, as1, ad1, N);
    gat1_agg<<<N, 128, 0, stream>>>(h1, r1, as1, ad1, offs, csr, g1b, hbuf, N);

    // --- GAT2 linear + residual linear ---
    {
        dim3 g((OUTC + 63) / 64, (N + 63) / 64);
        gemm_bias<false><<<g, 256, 0, stream>>>(hbuf, gat2_w, nullptr, h2, N, OUTC, 128);
        gemm_bias<false><<<g, 256, 0, stream>>>(hbuf, res2_w, res2_b, r2, N, OUTC, 128);
    }
    att2<<<(N + 255) / 256, 256, 0, stream>>>(h2, g2as, g2ad, as2, ad2, N);
    gat2_agg<<<N, 64, 0, stream>>>(h2, r2, as2, ad2, offs, csr, g2b, out, N);
}

// Round 2
// 507.585 us; speedup vs baseline: 1.6504x; 1.6504x over previous
//
#include <hip/hip_runtime.h>
#include <hip/hip_bf16.h>
#include <math.h>

#define HEADS 4
#define OUTC 40
#define SLOPE 0.2f

typedef __attribute__((ext_vector_type(8))) short bf16x8;
typedef __attribute__((ext_vector_type(4))) float f32x4;

__device__ __forceinline__ short f2bf(float f) {
    unsigned u = __float_as_uint(f);
    unsigned r = (u + 0x7FFFu + ((u >> 16) & 1u)) >> 16;
    return (short)r;
}
__device__ __forceinline__ float bf2f(short s) {
    return __uint_as_float(((unsigned)(unsigned short)s) << 16);
}

typedef const __attribute__((address_space(1))) unsigned int gu32;
typedef __attribute__((address_space(3))) unsigned int lu32;
__device__ __forceinline__ void gll16(const void* src, void* lds) {
    __builtin_amdgcn_global_load_lds((gu32*)src, (lu32*)lds, 16, 0, 0);
}

// ---------------------------------------------------------------------------
// Split-bf16 MFMA GEMM: C[M,N] = A[M,K] @ B[K,N], f32 precision via hi/lo bf16
// planes and 3 MFMA products. B is pre-split TRANSPOSED planes [N][K].
// Tile: BM=128, BN=128, BK=64. 256 threads = 4 waves (2x2), 64x64 per wave.
// AF32=1: A is raw f32 [M,K], split in-register (fc1). AF32=0: A hi/lo planes.
// EPI=0: out = relu(acc+bias) -> split bf16 planes Ohi/Olo [M][N].
// EPI=1: out f32, cols<128 -> O0[M,128], cols>=128 -> O1[M,128].
// ---------------------------------------------------------------------------
template<int AF32, int EPI>
__global__ __launch_bounds__(256) void gemm_mfma(
    const float* __restrict__ Af,
    const short* __restrict__ Ahi, const short* __restrict__ Alo,
    const short* __restrict__ Bhi, const short* __restrict__ Blo,
    const float* __restrict__ bias,
    short* __restrict__ Ohi, short* __restrict__ Olo,
    float* __restrict__ O0, float* __restrict__ O1,
    int M, int N, int K)
{
    __shared__ short smem[32768];          // 64 KB
    float* AsF = (float*)smem;             // AF32: 128x64 f32 (32 KB)
    short* AsH = smem;                     // planes: 128x64 bf16 (16 KB)
    short* AsL = smem + 8192;
    short* BsH = smem + 16384;             // 128x64 bf16 (16 KB)
    short* BsL = smem + 24576;

    const int tid = threadIdx.x;
    const int wid = tid >> 6, lane = tid & 63;
    const int bm = blockIdx.y * 128, bn = blockIdx.x * 128;
    const int wm = wid >> 1, wn = wid & 1;
    const int rA = lane & 15, kb = lane >> 4;

    f32x4 acc[4][4];
    #pragma unroll
    for (int i = 0; i < 4; i++)
        #pragma unroll
        for (int j = 0; j < 4; j++)
            acc[i][j] = (f32x4){0.f, 0.f, 0.f, 0.f};

    const int KT = K >> 6;
    for (int kt = 0; kt < KT; kt++) {
        const int k0 = kt << 6;
        // ---- stage A ----
        if (AF32) {
            #pragma unroll
            for (int it = 0; it < 8; it++) {
                int g = it * 256 + tid;
                int row = g >> 4, gr = g & 15;
                int gsrc = gr ^ (row & 15);
                int grow = bm + row; if (grow > M - 1) grow = M - 1;
                gll16(Af + (size_t)grow * K + k0 + gsrc * 4,
                      AsF + (it * 256 + wid * 64) * 4);
            }
        } else {
            #pragma unroll
            for (int p = 0; p < 2; p++) {
                const short* Ap = p ? Alo : Ahi;
                short* Ds = p ? AsL : AsH;
                #pragma unroll
                for (int it = 0; it < 4; it++) {
                    int g = it * 256 + tid;
                    int row = g >> 3, gr = g & 7;
                    int gsrc = gr ^ (row & 7);
                    int grow = bm + row; if (grow > M - 1) grow = M - 1;
                    gll16(Ap + (size_t)grow * K + k0 + gsrc * 8,
                          Ds + (it * 256 + wid * 64) * 8);
                }
            }
        }
        // ---- stage B (planes, transposed [N][K]) ----
        #pragma unroll
        for (int p = 0; p < 2; p++) {
            const short* Bp = p ? Blo : Bhi;
            short* Ds = p ? BsL : BsH;
            #pragma unroll
            for (int it = 0; it < 4; it++) {
                int g = it * 256 + tid;
                int row = g >> 3, gr = g & 7;
                int gsrc = gr ^ (row & 7);
                gll16(Bp + (size_t)(bn + row) * K + k0 + gsrc * 8,
                      Ds + (it * 256 + wid * 64) * 8);
            }
        }
        __syncthreads();
        // ---- compute ----
        #pragma unroll
        for (int kc = 0; kc < 2; kc++) {
            bf16x8 ah[4], al[4], bh[4], bl[4];
            if (AF32) {
                #pragma unroll
                for (int mi = 0; mi < 4; mi++) {
                    int r = wm * 64 + mi * 16 + rA;
                    int g0 = kc * 8 + kb * 2;
                    float4 f0 = *(const float4*)(AsF + r * 64 + ((g0 ^ (r & 15)) * 4));
                    float4 f1 = *(const float4*)(AsF + r * 64 + (((g0 + 1) ^ (r & 15)) * 4));
                    float fv[8] = {f0.x, f0.y, f0.z, f0.w, f1.x, f1.y, f1.z, f1.w};
                    #pragma unroll
                    for (int j = 0; j < 8; j++) {
                        short h = f2bf(fv[j]);
                        ah[mi][j] = h;
                        al[mi][j] = f2bf(fv[j] - bf2f(h));
                    }
                }
            } else {
                #pragma unroll
                for (int mi = 0; mi < 4; mi++) {
                    int r = wm * 64 + mi * 16 + rA;
                    int off = r * 64 + (((kc * 4 + kb) ^ (r & 7)) * 8);
                    ah[mi] = *(const bf16x8*)(AsH + off);
                    al[mi] = *(const bf16x8*)(AsL + off);
                }
            }
            #pragma unroll
            for (int ni = 0; ni < 4; ni++) {
                int r = wn * 64 + ni * 16 + rA;
                int off = r * 64 + (((kc * 4 + kb) ^ (r & 7)) * 8);
                bh[ni] = *(const bf16x8*)(BsH + off);
                bl[ni] = *(const bf16x8*)(BsL + off);
            }
            #pragma unroll
            for (int mi = 0; mi < 4; mi++)
                #pragma unroll
                for (int ni = 0; ni < 4; ni++) {
                    acc[mi][ni] = __builtin_amdgcn_mfma_f32_16x16x32_bf16(ah[mi], bh[ni], acc[mi][ni], 0, 0, 0);
                    acc[mi][ni] = __builtin_amdgcn_mfma_f32_16x16x32_bf16(ah[mi], bl[ni], acc[mi][ni], 0, 0, 0);
                    acc[mi][ni] = __builtin_amdgcn_mfma_f32_16x16x32_bf16(al[mi], bh[ni], acc[mi][ni], 0, 0, 0);
                }
        }
        __syncthreads();
    }

    // ---- epilogue (C/D map: col=lane&15, row=(lane>>4)*4+j) ----
    #pragma unroll
    for (int ni = 0; ni < 4; ni++) {
        int col = bn + wn * 64 + ni * 16 + rA;
        float bv = (EPI == 0) ? bias[col] : 0.f;
        #pragma unroll
        for (int mi = 0; mi < 4; mi++) {
            #pragma unroll
            for (int j = 0; j < 4; j++) {
                int row = bm + wm * 64 + mi * 16 + kb * 4 + j;
                if (row < M) {
                    float v = acc[mi][ni][j];
                    if (EPI == 0) {
                        v = fmaxf(v + bv, 0.f);
                        short h = f2bf(v);
                        Ohi[(size_t)row * N + col] = h;
                        Olo[(size_t)row * N + col] = f2bf(v - bf2f(h));
                    } else {
                        if (col < 128) O0[(size_t)row * 128 + col] = v;
                        else           O1[(size_t)row * 128 + (col - 128)] = v;
                    }
                }
            }
        }
    }
}

// ---------------------------------------------------------------------------
// f32 vector GEMM (kept for the small N=80 merged gat2/res2 matmul)
// ---------------------------------------------------------------------------
template<bool RELU>
__global__ __launch_bounds__(256) void gemm_bias(const float* __restrict__ A,
                                                 const float* __restrict__ B,
                                                 const float* __restrict__ bias,
                                                 float* __restrict__ C,
                                                 int M, int N, int K) {
    __shared__ float As[16][65];
    __shared__ float Bs[16][64];
    int tid = threadIdx.x;
    int tx = tid & 15, ty = tid >> 4;
    int bm = blockIdx.y * 64, bn = blockIdx.x * 64;
    int arow = tid >> 2, acol = (tid & 3) << 2;
    int brow = tid >> 4, bcol = (tid & 15) << 2;
    bool fullM = (bm + 64 <= M);
    bool fullN = (bn + 64 <= N);
    float acc[4][4] = {{0.f}};

    for (int k0 = 0; k0 < K; k0 += 16) {
        if (fullM) {
            const float4 av = *(const float4*)(A + (size_t)(bm + arow) * K + (k0 + acol));
            As[acol + 0][arow] = av.x; As[acol + 1][arow] = av.y;
            As[acol + 2][arow] = av.z; As[acol + 3][arow] = av.w;
        } else {
            int r = bm + arow;
            #pragma unroll
            for (int i = 0; i < 4; i++)
                As[acol + i][arow] = (r < M) ? A[(size_t)r * K + k0 + acol + i] : 0.f;
        }
        if (fullN) {
            *(float4*)(&Bs[brow][bcol]) = *(const float4*)(B + (size_t)(k0 + brow) * N + (bn + bcol));
        } else {
            #pragma unroll
            for (int i = 0; i < 4; i++) {
                int c = bn + bcol + i;
                Bs[brow][bcol + i] = (c < N) ? B[(size_t)(k0 + brow) * N + c] : 0.f;
            }
        }
        __syncthreads();
        #pragma unroll
        for (int kk = 0; kk < 16; kk++) {
            float a[4], b[4];
            #pragma unroll
            for (int i = 0; i < 4; i++) a[i] = As[kk][ty * 4 + i];
            #pragma unroll
            for (int j = 0; j < 4; j++) b[j] = Bs[kk][tx * 4 + j];
            #pragma unroll
            for (int i = 0; i < 4; i++)
                #pragma unroll
                for (int j = 0; j < 4; j++) acc[i][j] += a[i] * b[j];
        }
        __syncthreads();
    }

    #pragma unroll
    for (int i = 0; i < 4; i++) {
        int r = bm + ty * 4 + i;
        if (r < M) {
            #pragma unroll
            for (int j = 0; j < 4; j++) {
                int c = bn + tx * 4 + j;
                if (c < N) {
                    float v = acc[i][j] + (bias ? bias[c] : 0.f);
                    if (RELU) v = fmaxf(v, 0.f);
                    C[(size_t)r * N + c] = v;
                }
            }
        }
    }
}

// ---------------------------------------------------------------------------
// Weight conversion kernels
// ---------------------------------------------------------------------------
__global__ void wt_split(const float* __restrict__ Wm, int K, int Nn,
                         short* __restrict__ hi, short* __restrict__ lo) {
    int idx = blockIdx.x * blockDim.x + threadIdx.x;
    if (idx >= K * Nn) return;
    int n = idx / K, k = idx - n * K;
    float v = Wm[(size_t)k * Nn + n];
    short h = f2bf(v);
    hi[idx] = h; lo[idx] = f2bf(v - bf2f(h));
}

__global__ void wt_split2(const float* __restrict__ Wg, const float* __restrict__ Wr,
                          int K, int Nh, short* __restrict__ hi, short* __restrict__ lo) {
    int idx = blockIdx.x * blockDim.x + threadIdx.x;
    if (idx >= K * 2 * Nh) return;
    int n = idx / K, k = idx - n * K;
    float v = (n < Nh) ? Wg[(size_t)k * Nh + n] : Wr[(size_t)k * Nh + (n - Nh)];
    short h = f2bf(v);
    hi[idx] = h; lo[idx] = f2bf(v - bf2f(h));
}

__global__ void build_wc2(const float* __restrict__ g2w, const float* __restrict__ r2w,
                          const float* __restrict__ r2b,
                          float* __restrict__ wc2, float* __restrict__ cb2) {
    int idx = blockIdx.x * blockDim.x + threadIdx.x;
    if (idx < 128 * 80) {
        int k = idx / 80, n = idx - k * 80;
        wc2[idx] = (n < 40) ? g2w[k * 40 + n] : r2w[k * 40 + (n - 40)];
    }
    if (idx < 80) cb2[idx] = (idx < 40) ? 0.f : r2b[idx - 40];
}

// ---------------------------------------------------------------------------
// CSR build
// ---------------------------------------------------------------------------
__global__ void count_deg(const int* __restrict__ dstA, int E, int* __restrict__ deg) {
    int e = blockIdx.x * blockDim.x + threadIdx.x;
    if (e < E) atomicAdd(&deg[dstA[e]], 1);
}

__global__ void scan_part(const int* __restrict__ deg, int N, int* __restrict__ part) {
    __shared__ int s[256];
    int b = blockIdx.x, t = threadIdx.x;
    int i0 = b * 1024 + t * 4;
    int sum = 0;
    #pragma unroll
    for (int j = 0; j < 4; j++) { int i = i0 + j; if (i < N) sum += deg[i] + 1; }
    s[t] = sum; __syncthreads();
    for (int o = 128; o; o >>= 1) { if (t < o) s[t] += s[t + o]; __syncthreads(); }
    if (t == 0) part[b] = s[0];
}

__global__ void scan_base(int* __restrict__ part, int nb, int* __restrict__ offs) {
    int t = threadIdx.x;
    int v = (t < nb) ? part[t] : 0;
    int v0 = v;
    for (int o = 1; o < 64; o <<= 1) {
        int u = __shfl_up(v, o, 64);
        if (t >= o) v += u;
    }
    if (t < nb) part[t] = v - v0;   // exclusive
    if (t == 0) offs[0] = 0;
}

__global__ void scan_final(const int* __restrict__ deg, int N, const int* __restrict__ part,
                           int* __restrict__ offs, int* __restrict__ cur) {
    __shared__ int s[256];
    int b = blockIdx.x, t = threadIdx.x;
    int i0 = b * 1024 + t * 4;
    int v[4]; int sum = 0;
    #pragma unroll
    for (int j = 0; j < 4; j++) { int i = i0 + j; v[j] = (i < N) ? deg[i] + 1 : 0; sum += v[j]; }
    s[t] = sum; __syncthreads();
    for (int o = 1; o < 256; o <<= 1) {
        int add = (t >= o) ? s[t - o] : 0;
        __syncthreads();
        s[t] += add;
        __syncthreads();
    }
    int excl = s[t] - sum + part[b];
    #pragma unroll
    for (int j = 0; j < 4; j++) {
        int i = i0 + j;
        if (i < N) { cur[i] = excl; offs[i + 1] = excl + v[j]; excl += v[j]; }
    }
}

__global__ void scatter_k(const int* __restrict__ srcA, const int* __restrict__ dstA,
                          int E, int* __restrict__ cur, int* __restrict__ csr) {
    int e = blockIdx.x * blockDim.x + threadIdx.x;
    if (e < E) {
        int p = atomicAdd(&cur[dstA[e]], 1);
        csr[p] = srcA[e];
    }
}

__global__ void selfloop_k(const int* __restrict__ offs, int* __restrict__ csr, int N) {
    int n = blockIdx.x * blockDim.x + threadIdx.x;
    if (n < N) csr[offs[n + 1] - 1] = n;
}

// ---------------------------------------------------------------------------
// Attention score vectors
// ---------------------------------------------------------------------------
__global__ void att1(const float* __restrict__ h1, const float* __restrict__ atts,
                     const float* __restrict__ attd, float* __restrict__ as1,
                     float* __restrict__ ad1, int N) {
    int idx = blockIdx.x * blockDim.x + threadIdx.x;
    if (idx >= N * HEADS) return;
    int n = idx >> 2, h = idx & 3;
    const float* row = h1 + (size_t)n * 128 + h * 32;
    float ss = 0.f, dd = 0.f;
    #pragma unroll
    for (int c = 0; c < 32; c++) {
        float v = row[c];
        ss += v * atts[h * 32 + c];
        dd += v * attd[h * 32 + c];
    }
    as1[idx] = ss; ad1[idx] = dd;
}

__global__ void att2(const float* __restrict__ h2r2, const float* __restrict__ atts,
                     const float* __restrict__ attd, float* __restrict__ as2,
                     float* __restrict__ ad2, int N) {
    int n = blockIdx.x * blockDim.x + threadIdx.x;
    if (n >= N) return;
    const float* row = h2r2 + (size_t)n * 80;
    float ss = 0.f, dd = 0.f;
    #pragma unroll
    for (int c = 0; c < OUTC; c++) {
        float v = row[c];
        ss += v * atts[c];
        dd += v * attd[c];
    }
    as2[n] = ss; ad2[n] = dd;
}

// ---------------------------------------------------------------------------
// GAT aggregations
// ---------------------------------------------------------------------------
__global__ __launch_bounds__(128) void gat1_agg(const float* __restrict__ h1,
                                                const float* __restrict__ r1,
                                                const float* __restrict__ as1,
                                                const float* __restrict__ ad1,
                                                const int* __restrict__ offs,
                                                const int* __restrict__ csr,
                                                const float* __restrict__ gb,
                                                const float* __restrict__ rb,
                                                float* __restrict__ outh, int N) {
    int n = blockIdx.x;
    int t = threadIdx.x;
    int h = t >> 5;
    int l = t & 31;
    int beg = offs[n], d = offs[n + 1] - beg;
    float adst = ad1[n * HEADS + h];

    float mx = -INFINITY;
    for (int j = l; j < d; j += 32) {
        int s = csr[beg + j];
        float v = as1[s * HEADS + h] + adst;
        v = v >= 0.f ? v : SLOPE * v;
        mx = fmaxf(mx, v);
    }
    for (int o = 16; o; o >>= 1) mx = fmaxf(mx, __shfl_xor(mx, o, 32));

    float den = 0.f;
    for (int j = l; j < d; j += 32) {
        int s = csr[beg + j];
        float v = as1[s * HEADS + h] + adst;
        v = v >= 0.f ? v : SLOPE * v;
        den += __expf(v - mx);
    }
    for (int o = 16; o; o >>= 1) den += __shfl_xor(den, o, 32);
    den = fmaxf(den, 1e-16f);

    float acc = 0.f;
    for (int j = 0; j < d; j++) {
        int s = csr[beg + j];
        float v = as1[s * HEADS + h] + adst;
        v = v >= 0.f ? v : SLOPE * v;
        float w = __expf(v - mx);
        acc += w * h1[(size_t)s * 128 + t];
    }
    float v = acc / den + gb[t] + rb[t] + r1[(size_t)n * 128 + t];
    outh[(size_t)n * 128 + t] = fmaxf(v, 0.f);
}

__global__ __launch_bounds__(64) void gat2_agg(const float* __restrict__ h2r2,
                                               const float* __restrict__ as2,
                                               const float* __restrict__ ad2,
                                               const int* __restrict__ offs,
                                               const int* __restrict__ csr,
                                               const float* __restrict__ gb,
                                               float* __restrict__ out, int N) {
    int n = blockIdx.x;
    int t = threadIdx.x;
    int beg = offs[n], d = offs[n + 1] - beg;
    float adst = ad2[n];

    float mx = -INFINITY;
    for (int j = t; j < d; j += 64) {
        int s = csr[beg + j];
        float v = as2[s] + adst;
        v = v >= 0.f ? v : SLOPE * v;
        mx = fmaxf(mx, v);
    }
    for (int o = 32; o; o >>= 1) mx = fmaxf(mx, __shfl_xor(mx, o, 64));

    float den = 0.f;
    for (int j = t; j < d; j += 64) {
        int s = csr[beg + j];
        float v = as2[s] + adst;
        v = v >= 0.f ? v : SLOPE * v;
        den += __expf(v - mx);
    }
    for (int o = 32; o; o >>= 1) den += __shfl_xor(den, o, 64);
    den = fmaxf(den, 1e-16f);

    if (t < OUTC) {
        float acc = 0.f;
        for (int j = 0; j < d; j++) {
            int s = csr[beg + j];
            float v = as2[s] + adst;
            v = v >= 0.f ? v : SLOPE * v;
            float w = __expf(v - mx);
            acc += w * h2r2[(size_t)s * 80 + t];
        }
        out[(size_t)n * OUTC + t] = acc / den + gb[t] + h2r2[(size_t)n * 80 + 40 + t];
    }
}

// ---------------------------------------------------------------------------
// Launcher
// ---------------------------------------------------------------------------
extern "C" void kernel_launch(void* const* d_in, const int* in_sizes, int n_in,
                              void* d_out, int out_size, void* d_ws, size_t ws_size,
                              hipStream_t stream) {
    const float* x      = (const float*)d_in[0];
    const int*   ei     = (const int*)d_in[1];
    const float* ae_w1  = (const float*)d_in[2];
    const float* ae_b1  = (const float*)d_in[3];
    const float* ae_w2  = (const float*)d_in[4];
    const float* ae_b2  = (const float*)d_in[5];
    const float* gat1_w = (const float*)d_in[6];
    const float* g1as   = (const float*)d_in[7];
    const float* g1ad   = (const float*)d_in[8];
    const float* g1b    = (const float*)d_in[9];
    const float* gat2_w = (const float*)d_in[10];
    const float* g2as   = (const float*)d_in[11];
    const float* g2ad   = (const float*)d_in[12];
    const float* g2b    = (const float*)d_in[13];
    const float* res1_w = (const float*)d_in[14];
    const float* res1_b = (const float*)d_in[15];
    const float* res2_w = (const float*)d_in[16];
    const float* res2_b = (const float*)d_in[17];
    float* out = (float*)d_out;

    const int Nn = in_sizes[0] / 512;       // 50000 nodes
    const int E  = in_sizes[1] / 2;         // 800000 edges

    const int* srcA = ei;
    const int* dstA = ei + E;

    // ---- workspace layout (bytes) ----
    char* W = (char*)d_ws;
    size_t off = 0;
    auto alloc = [&](size_t bytes) { char* p = W + off; off += (bytes + 255) & ~(size_t)255; return p; };

    const size_t regA = (size_t)Nn * 256 * 2;   // 25.6 MB (one plane) == Nn*128*4
    char* pA = alloc(2 * regA);                 // y1 planes -> later h1 | r1
    short* y1hi = (short*)pA;
    short* y1lo = (short*)(pA + regA);
    float* h1   = (float*)pA;
    float* r1   = (float*)(pA + regA);

    char* pB = alloc(2 * regA);                 // xe planes -> later hbuf | h2r2
    short* xehi = (short*)pB;
    short* xelo = (short*)(pB + regA);
    float* hbuf = (float*)pB;
    float* h2r2 = (float*)(pB + regA);          // [Nn,80]

    short* w1Thi = (short*)alloc(256 * 512 * 2);
    short* w1Tlo = (short*)alloc(256 * 512 * 2);
    short* w2Thi = (short*)alloc(256 * 256 * 2);
    short* w2Tlo = (short*)alloc(256 * 256 * 2);
    short* wc1hi = (short*)alloc(256 * 256 * 2);
    short* wc1lo = (short*)alloc(256 * 256 * 2);
    float* wc2   = (float*)alloc(128 * 80 * 4);
    float* cb2   = (float*)alloc(128 * 4);
    float* as1   = (float*)alloc((size_t)Nn * HEADS * 4);
    float* ad1   = (float*)alloc((size_t)Nn * HEADS * 4);
    float* as2   = (float*)alloc((size_t)Nn * 4);
    float* ad2   = (float*)alloc((size_t)Nn * 4);
    int* deg  = (int*)alloc((size_t)Nn * 4);
    int* offs = (int*)alloc((size_t)(Nn + 1) * 4);
    int* cur  = (int*)alloc((size_t)Nn * 4);
    int* part = (int*)alloc(256 * 4);
    int* csr  = (int*)alloc((size_t)(E + Nn) * 4);

    // ---- weight prep ----
    wt_split<<<(512 * 256 + 255) / 256, 256, 0, stream>>>(ae_w1, 512, 256, w1Thi, w1Tlo);
    wt_split<<<(256 * 256 + 255) / 256, 256, 0, stream>>>(ae_w2, 256, 256, w2Thi, w2Tlo);
    wt_split2<<<(256 * 256 + 255) / 256, 256, 0, stream>>>(gat1_w, res1_w, 256, 128, wc1hi, wc1lo);
    build_wc2<<<(128 * 80 + 255) / 256, 256, 0, stream>>>(gat2_w, res2_w, res2_b, wc2, cb2);

    // ---- CSR build ----
    hipMemsetAsync(deg, 0, (size_t)Nn * sizeof(int), stream);
    count_deg<<<(E + 255) / 256, 256, 0, stream>>>(dstA, E, deg);
    int nb = (Nn + 1023) / 1024;
    scan_part<<<nb, 256, 0, stream>>>(deg, Nn, part);
    scan_base<<<1, 64, 0, stream>>>(part, nb, offs);
    scan_final<<<nb, 256, 0, stream>>>(deg, Nn, part, offs, cur);
    scatter_k<<<(E + 255) / 256, 256, 0, stream>>>(srcA, dstA, E, cur, csr);
    selfloop_k<<<(Nn + 255) / 256, 256, 0, stream>>>(offs, csr, Nn);

    const int gy = (Nn + 127) / 128;   // 391

    // ---- fc1: relu(x @ ae_w1 + b1) -> y1 planes ----
    gemm_mfma<1, 0><<<dim3(2, gy), 256, 0, stream>>>(
        x, nullptr, nullptr, w1Thi, w1Tlo, ae_b1,
        y1hi, y1lo, nullptr, nullptr, Nn, 256, 512);

    // ---- fc2: relu(y1 @ ae_w2 + b2) -> xe planes ----
    gemm_mfma<0, 0><<<dim3(2, gy), 256, 0, stream>>>(
        nullptr, y1hi, y1lo, w2Thi, w2Tlo, ae_b2,
        xehi, xelo, nullptr, nullptr, Nn, 256, 256);

    // ---- gatres1: xe @ [gat1_w | res1_w] -> h1 [Nn,128], r1 [Nn,128] ----
    gemm_mfma<0, 1><<<dim3(2, gy), 256, 0, stream>>>(
        nullptr, xehi, xelo, wc1hi, wc1lo, nullptr,
        nullptr, nullptr, h1, r1, Nn, 256, 256);

    att1<<<(Nn * HEADS + 255) / 256, 256, 0, stream>>>(h1, g1as, g1ad, as1, ad1, Nn);
    gat1_agg<<<Nn, 128, 0, stream>>>(h1, r1, as1, ad1, offs, csr, g1b, res1_b, hbuf, Nn);

    // ---- gatres2 (f32): hbuf @ [gat2_w | res2_w] + [0|res2_b] -> h2r2 [Nn,80] ----
    gemm_bias<false><<<dim3(2, (Nn + 63) / 64), 256, 0, stream>>>(hbuf, wc2, cb2, h2r2, Nn, 80, 128);

    att2<<<(Nn + 255) / 256, 256, 0, stream>>>(h2r2, g2as, g2ad, as2, ad2, Nn);
    gat2_agg<<<Nn, 64, 0, stream>>>(h2r2, as2, ad2, offs, csr, g2b, out, Nn);
}